// Round 1
// baseline (1021.620 us; speedup 1.0000x reference)
//
#include <hip/hip_runtime.h>
#include <hip/hip_fp8.h>

#define T_DIM 2048
#define D_DIM 4096
#define I_DIM 11008

typedef int v8i __attribute__((ext_vector_type(8)));
typedef float v4f __attribute__((ext_vector_type(4)));

__device__ inline unsigned char to_fp8(float f) {
  return (unsigned char)__hip_cvt_float_to_fp8(f, __HIP_SATFINITE, __HIP_E4M3);
}

__device__ inline void async_copy16(const void* g, void* l) {
  __builtin_amdgcn_global_load_lds((const __attribute__((address_space(1))) void*)g,
                                   (__attribute__((address_space(3))) void*)l, 16, 0, 0);
}

// ---------------------------------------------------------------------------
// Act quant: per-(row,128-block) amax -> scale -> fp8. One wave per block.
// Scales stored TRANSPOSED: St[kb][t] so the GEMM can read 128 consecutive
// row-scales for a tile column with float4 loads.
// ---------------------------------------------------------------------------
__global__ void quant_x_kernel(const float* __restrict__ X, unsigned char* __restrict__ Q,
                               float* __restrict__ St, const int T, const int D) {
  const int wave = (blockIdx.x << 2) + (threadIdx.x >> 6);
  const int lane = threadIdx.x & 63;
  const int nb = D >> 7;
  const int t = wave / nb;
  const int kb = wave - t * nb;
  const size_t base = (size_t)t * D + ((size_t)kb << 7);
  const float2 v = ((const float2*)(X + base))[lane];
  float a = fmaxf(fabsf(v.x), fabsf(v.y));
#pragma unroll
  for (int off = 32; off > 0; off >>= 1) a = fmaxf(a, __shfl_xor(a, off));
  const float scale = (a == 0.f) ? 1.f : (a / 448.f);
  unsigned short pk = (unsigned short)to_fp8(v.x / scale) |
                      ((unsigned short)to_fp8(v.y / scale) << 8);
  ((unsigned short*)(Q + base))[lane] = pk;
  if (lane == 0) St[(size_t)kb * T + t] = scale;
}

// ---------------------------------------------------------------------------
// silu(h1)*h3, then per-128-block quantization (fused epilogue of GEMM1/3).
// ---------------------------------------------------------------------------
__global__ void silu_mul_quant_kernel(const float* __restrict__ H1, const float* __restrict__ H3,
                                      unsigned char* __restrict__ Q, float* __restrict__ St,
                                      const int T, const int D) {
  const int wave = (blockIdx.x << 2) + (threadIdx.x >> 6);
  const int lane = threadIdx.x & 63;
  const int nb = D >> 7;
  const int t = wave / nb;
  const int kb = wave - t * nb;
  const size_t base = (size_t)t * D + ((size_t)kb << 7);
  const float2 v1 = ((const float2*)(H1 + base))[lane];
  const float2 v3 = ((const float2*)(H3 + base))[lane];
  const float hx = (v1.x / (1.f + expf(-v1.x))) * v3.x;
  const float hy = (v1.y / (1.f + expf(-v1.y))) * v3.y;
  float a = fmaxf(fabsf(hx), fabsf(hy));
#pragma unroll
  for (int off = 32; off > 0; off >>= 1) a = fmaxf(a, __shfl_xor(a, off));
  const float scale = (a == 0.f) ? 1.f : (a / 448.f);
  unsigned short pk = (unsigned short)to_fp8(hx / scale) |
                      ((unsigned short)to_fp8(hy / scale) << 8);
  ((unsigned short*)(Q + base))[lane] = pk;
  if (lane == 0) St[(size_t)kb * T + t] = scale;
}

// ---------------------------------------------------------------------------
// Weight convert fp32 -> fp8 (values are exactly fp8-representable).
// ---------------------------------------------------------------------------
__global__ void convert_fp8_kernel(const float4* __restrict__ W, unsigned int* __restrict__ Q,
                                   const int n4) {
  const int i = blockIdx.x * 256 + threadIdx.x;
  if (i >= n4) return;
  const float4 f = W[i];
  Q[i] = (unsigned int)to_fp8(f.x) | ((unsigned int)to_fp8(f.y) << 8) |
         ((unsigned int)to_fp8(f.z) << 16) | ((unsigned int)to_fp8(f.w) << 24);
}

// ---------------------------------------------------------------------------
// fp8 block-scaled GEMM:  C[M][N] = sum_kb sA[m,kb]*sB[n/128,kb] * (Aq Bq^T)
// A: [M][K] fp8 row-major, B: [N][K] fp8 row-major (i.e. B^T layout).
// 128x128 tile, BK=128 (one scale block per K-iter), 4 waves of 64x64.
// mfma_scale_f32_16x16x128_f8f6f4 with unit e8m0 scales; fp32 block scales
// folded with per-row v_fmac each K-iter (DeepSeek promotion-every-128).
// ---------------------------------------------------------------------------
__global__ __launch_bounds__(256, 2) void gemm_fp8_bs(
    const unsigned char* __restrict__ A, const float* __restrict__ sAt,
    const unsigned char* __restrict__ B, const float* __restrict__ sB,
    float* __restrict__ C, const int M, const int N, const int K) {
  __shared__ unsigned char As[128 * 128];
  __shared__ unsigned char Bs[128 * 128];

  const int tid = threadIdx.x;
  const int lane = tid & 63;
  const int w = tid >> 6;
  const int wm = (w >> 1) << 6;   // wave row offset within 128-tile
  const int wn = (w & 1) << 6;    // wave col offset
  const int row16 = lane & 15;
  const int quad = lane >> 4;
  const int m0 = blockIdx.x << 7;
  const int n0 = blockIdx.y << 7;
  const int nkb = K >> 7;

  // staging: per wave, 4 instrs x 64 lanes x 16B = 4096B (32 rows of 128B)
  const int srow = (w << 5) + (lane >> 3);
  const int scol = (lane & 7) << 4;
  const unsigned char* gA = A + (size_t)(m0 + srow) * K + scol;
  const unsigned char* gB = B + (size_t)(n0 + srow) * K + scol;
  unsigned char* lA = &As[w << 12];
  unsigned char* lB = &Bs[w << 12];

  v4f zero = {0.f, 0.f, 0.f, 0.f};
  v4f acc[4][4];
#pragma unroll
  for (int i = 0; i < 4; ++i)
#pragma unroll
    for (int j = 0; j < 4; ++j) acc[i][j] = zero;

  const float* sArow = sAt + m0 + wm + (quad << 2);  // + kb*M, float4 covers 4 regs
  const float* sBrow = sB + (size_t)(n0 >> 7) * nkb;

  for (int kb = 0; kb < nkb; ++kb) {
    __syncthreads();
    const size_t koff = (size_t)kb << 7;
#pragma unroll
    for (int t = 0; t < 4; ++t)
      async_copy16(gA + (size_t)(t * 8) * K + koff, lA + (t << 10));
#pragma unroll
    for (int t = 0; t < 4; ++t)
      async_copy16(gB + (size_t)(t * 8) * K + koff, lB + (t << 10));

    const float sb = sBrow[kb];
    float4 sa[4];
    const float4* sap = (const float4*)(sArow + (size_t)kb * M);
#pragma unroll
    for (int i = 0; i < 4; ++i) sa[i] = sap[i * 4];

    __syncthreads();

    v8i a[4], b[4];
#pragma unroll
    for (int i = 0; i < 4; ++i)
      a[i] = *(const v8i*)&As[((wm + (i << 4) + row16) << 7) + (quad << 5)];
#pragma unroll
    for (int j = 0; j < 4; ++j)
      b[j] = *(const v8i*)&Bs[((wn + (j << 4) + row16) << 7) + (quad << 5)];

#pragma unroll
    for (int i = 0; i < 4; ++i) {
      v4f cs;
      cs.x = sa[i].x * sb; cs.y = sa[i].y * sb;
      cs.z = sa[i].z * sb; cs.w = sa[i].w * sb;
#pragma unroll
      for (int j = 0; j < 4; ++j) {
        v4f p = __builtin_amdgcn_mfma_scale_f32_16x16x128_f8f6f4(
            a[i], b[j], zero, 0, 0, 0, 0x7f7f7f7f, 0, 0x7f7f7f7f);
        acc[i][j] += cs * p;
      }
    }
  }

  // epilogue: C/D layout col=lane&15, row=quad*4+reg
#pragma unroll
  for (int i = 0; i < 4; ++i) {
    const size_t rbase = (size_t)(m0 + wm + (i << 4) + (quad << 2));
#pragma unroll
    for (int r = 0; r < 4; ++r) {
      float* crow = C + (rbase + r) * N + n0 + wn + row16;
#pragma unroll
      for (int j = 0; j < 4; ++j) crow[j << 4] = acc[i][j][r];
    }
  }
}

extern "C" void kernel_launch(void* const* d_in, const int* in_sizes, int n_in,
                              void* d_out, int out_size, void* d_ws, size_t ws_size,
                              hipStream_t stream) {
  const float* x   = (const float*)d_in[0];
  const float* w1q = (const float*)d_in[1];
  const float* w1s = (const float*)d_in[2];
  const float* w2q = (const float*)d_in[3];
  const float* w2s = (const float*)d_in[4];
  const float* w3q = (const float*)d_in[5];
  const float* w3s = (const float*)d_in[6];

  unsigned char* ws = (unsigned char*)d_ws;
  const size_t SZ_QX = (size_t)T_DIM * D_DIM;          // 8,388,608
  const size_t SZ_W  = (size_t)I_DIM * D_DIM;          // 45,088,768 (per weight)
  const size_t SZ_QH = (size_t)T_DIM * I_DIM;          // 22,544,384
  const size_t SZ_SX = (size_t)(D_DIM / 128) * T_DIM * 4;
  const size_t SZ_SH = (size_t)(I_DIM / 128) * T_DIM * 4;
  const size_t SZ_H  = (size_t)T_DIM * I_DIM * 4;      // 90,177,536

  unsigned char* qx   = ws;             ws += SZ_QX;
  unsigned char* w1q8 = ws;             ws += SZ_W;
  unsigned char* w3q8 = ws;             ws += SZ_W;
  unsigned char* w2q8 = ws;             ws += SZ_W;
  unsigned char* qh   = ws;             ws += SZ_QH;
  float* sxt = (float*)ws;              ws += SZ_SX;
  float* sht = (float*)ws;              ws += SZ_SH;
  float* h1  = (float*)ws;              ws += SZ_H;
  float* h3  = (float*)ws;              ws += SZ_H;

  // 1. quantize x: 2048*32 waves / 4 per block
  quant_x_kernel<<<(T_DIM * (D_DIM / 128)) / 4, 256, 0, stream>>>(x, qx, sxt, T_DIM, D_DIM);

  // 2. convert weights fp32 -> fp8 (exact)
  const int n4w = (int)(SZ_W / 4);  // 11,272,192 -> 44032 blocks
  convert_fp8_kernel<<<(n4w + 255) / 256, 256, 0, stream>>>((const float4*)w1q, (unsigned int*)w1q8, n4w);
  convert_fp8_kernel<<<(n4w + 255) / 256, 256, 0, stream>>>((const float4*)w3q, (unsigned int*)w3q8, n4w);
  convert_fp8_kernel<<<(n4w + 255) / 256, 256, 0, stream>>>((const float4*)w2q, (unsigned int*)w2q8, n4w);

  // 3. GEMM1 / GEMM3: [2048,4096] x [11008,4096]^T -> h1/h3 fp32
  dim3 g13(T_DIM / 128, I_DIM / 128);
  gemm_fp8_bs<<<g13, 256, 0, stream>>>(qx, sxt, w1q8, w1s, h1, T_DIM, I_DIM, D_DIM);
  gemm_fp8_bs<<<g13, 256, 0, stream>>>(qx, sxt, w3q8, w3s, h3, T_DIM, I_DIM, D_DIM);

  // 4. h = silu(h1)*h3, quantized per 128-block
  silu_mul_quant_kernel<<<(T_DIM * (I_DIM / 128)) / 4, 256, 0, stream>>>(h1, h3, qh, sht, T_DIM, I_DIM);

  // 5. GEMM2: [2048,11008] x [4096,11008]^T -> out fp32
  dim3 g2(T_DIM / 128, D_DIM / 128);
  gemm_fp8_bs<<<g2, 256, 0, stream>>>(qh, sht, w2q8, w2s, (float*)d_out, T_DIM, D_DIM, I_DIM);

  (void)in_sizes; (void)n_in; (void)out_size; (void)ws_size;
}